// Round 2
// baseline (728.757 us; speedup 1.0000x reference)
//
#include <hip/hip_runtime.h>
#include <hip/hip_bf16.h>
#include <math.h>

#define NN 2048
#define CC 256
#define KK 16
#define SS 128
#define HH 8
#define DH 64
#define INNER 512

// ---------------- helpers ----------------

__device__ __forceinline__ void block_reduce2(float v1, float v2, float* red, float& o1, float& o2) {
  // 256 threads = 4 waves; red has >= 8 floats
  #pragma unroll
  for (int o = 32; o > 0; o >>= 1) { v1 += __shfl_xor(v1, o, 64); v2 += __shfl_xor(v2, o, 64); }
  int wid = threadIdx.x >> 6;
  if ((threadIdx.x & 63) == 0) { red[wid] = v1; red[4 + wid] = v2; }
  __syncthreads();
  o1 = red[0] + red[1] + red[2] + red[3];
  o2 = red[4] + red[5] + red[6] + red[7];
}

// ---------------- adjacency ----------------

__global__ void build_maps(const int* __restrict__ clusters, int* __restrict__ node2c,
                           int* __restrict__ node2p) {
  int r = blockIdx.x * 256 + threadIdx.x;   // 0..2047 (k*S+s)
  int node = clusters[r];
  node2c[node] = r >> 7;
  node2p[node] = r & 127;
}

__global__ void build_adj(const int* __restrict__ ei, const int* __restrict__ node2c,
                          const int* __restrict__ node2p, unsigned* __restrict__ adj, int E) {
  int t = blockIdx.x * 256 + threadIdx.x;
  if (t >= E) return;
  int u = ei[t], v = ei[E + t];
  int cu = node2c[u];
  if (cu == node2c[v]) {
    int pu = node2p[u], pv = node2p[v];
    atomicOr(&adj[(cu * 128 + pu) * 4 + (pv >> 5)], 1u << (pv & 31));
  }
}

// e0 = adj_emb[0]@We + be ; e1 = adj_emb[1]@We + be   -> e01[0:512], e01[512:1024]
__global__ void e01_kernel(const float* __restrict__ adj_emb, const float* __restrict__ We,
                           const float* __restrict__ be, float* __restrict__ e01) {
  int j = threadIdx.x;  // 0..511
  float a0 = 0.f, a1 = 0.f;
  for (int c = 0; c < CC; ++c) {
    float w = We[(size_t)c * INNER + j];
    a0 = fmaf(adj_emb[c], w, a0);
    a1 = fmaf(adj_emb[CC + c], w, a1);
  }
  e01[j] = a0 + be[j];
  e01[INNER + j] = a1 + be[j];
}

// ---------------- layernorm (optional gather) ----------------

__global__ __launch_bounds__(256) void ln_kernel(const float* __restrict__ src,
    const int* __restrict__ cl, const float* __restrict__ g, const float* __restrict__ b,
    float* __restrict__ outp) {
  __shared__ float red[8];
  int row = blockIdx.x;
  int node = cl ? cl[row] : row;
  int c = threadIdx.x;
  float v = src[(size_t)node * CC + c];
  float s, s2;
  block_reduce2(v, v * v, red, s, s2);
  float m = s * (1.f / CC);
  float var = s2 * (1.f / CC) - m * m;
  float r = rsqrtf(var + 1e-5f);
  outp[(size_t)row * CC + c] = (v - m) * r * g[c] + b[c];
}

// ---------------- streaming GEMM:  C[M,N] = A[M,K] @ B[K,N] + bias (opt gelu) ----------------

template <int EPI, int ROWS>
__global__ __launch_bounds__(256) void gemm_rows(const float* __restrict__ A,
    const float* __restrict__ B, const float* __restrict__ bias, float* __restrict__ C_,
    int Kd, int Nd) {
  int row0 = blockIdx.x * ROWS;
  int col = blockIdx.y * 256 + threadIdx.x;
  float acc[ROWS];
  #pragma unroll
  for (int r = 0; r < ROWS; ++r) acc[r] = 0.f;
  for (int k = 0; k < Kd; ++k) {
    float bv = B[(size_t)k * Nd + col];
    #pragma unroll
    for (int r = 0; r < ROWS; ++r)
      acc[r] = fmaf(A[(size_t)(row0 + r) * Kd + k], bv, acc[r]);
  }
  float bb = bias[col];
  #pragma unroll
  for (int r = 0; r < ROWS; ++r) {
    float v = acc[r] + bb;
    if (EPI == 1) v = 0.5f * v * (1.f + erff(v * 0.70710678118654752f));
    C_[(size_t)(row0 + r) * Nd + col] = v;
  }
}

// ---------------- rotary (in-place on q and k-half of kv) ----------------

__global__ __launch_bounds__(256) void rotary_kernel(float* __restrict__ q, float* __restrict__ kv) {
  int row = blockIdx.x;          // 0..2047
  int p = threadIdx.x;           // pair id 0..255
  int head = p >> 5, tp = p & 31;
  int col = head * DH + tp * 2;
  float s = (float)(row & (SS - 1));
  float inv = powf(10000.f, -(float)tp / 32.f);
  float ang = s * inv;
  float cs, sn;
  sincosf(ang, &sn, &cs);   // FIX: sincosf(x, sin*, cos*) — sin pointer comes FIRST
  float* qp = q + (size_t)row * INNER + col;
  float x1 = qp[0], x2 = qp[1];
  qp[0] = x1 * cs - x2 * sn;
  qp[1] = x2 * cs + x1 * sn;
  float* kp = kv + (size_t)row * (2 * INNER) + col;
  x1 = kp[0]; x2 = kp[1];
  kp[0] = x1 * cs - x2 * sn;
  kp[1] = x2 * cs + x1 * sn;
}

// ---------------- attention: one block per (cluster, head) ----------------

__global__ __launch_bounds__(128) void attn_kernel(const float* __restrict__ q,
    const float* __restrict__ kv, const unsigned* __restrict__ adj,
    const float* __restrict__ e01, float* __restrict__ outp) {
  __shared__ float ksh[SS][DH];
  __shared__ float e0sh[DH], e1sh[DH];
  int kk = blockIdx.x >> 3;
  int h = blockIdx.x & 7;
  int tid = threadIdx.x;

  // stage K rows for this (cluster, head) into LDS (128x64 f32 = 32KB)
  for (int f = tid; f < SS * (DH / 4); f += 128) {   // f indexes float4s, 16 per row
    int row = f >> 4, c4 = f & 15;
    const float4* src = (const float4*)(kv + ((size_t)(kk * SS + row)) * (2 * INNER) + h * DH) + c4;
    ((float4*)&ksh[0][0])[f] = *src;
  }
  if (tid < 64) e0sh[tid] = e01[h * DH + tid];
  else e1sh[tid - 64] = e01[INNER + h * DH + (tid - 64)];
  __syncthreads();

  int i = tid;  // query row
  float qreg[DH];
  const float4* qp = (const float4*)(q + ((size_t)(kk * SS + i)) * INNER + h * DH);
  #pragma unroll
  for (int d4 = 0; d4 < 16; ++d4) {
    float4 t = qp[d4];
    qreg[d4 * 4 + 0] = t.x; qreg[d4 * 4 + 1] = t.y;
    qreg[d4 * 4 + 2] = t.z; qreg[d4 * 4 + 3] = t.w;
  }
  float qe0 = 0.f, qe1 = 0.f;
  #pragma unroll
  for (int d = 0; d < DH; ++d) {
    qe0 = fmaf(qreg[d], e0sh[d], qe0);
    qe1 = fmaf(qreg[d], e1sh[d], qe1);
  }
  int rb = (kk * SS + i) * 4;
  unsigned aw0 = adj[rb + 0], aw1 = adj[rb + 1], aw2 = adj[rb + 2], aw3 = adj[rb + 3];

  // pass 1: online max & denom
  float m = -1e30f, l = 0.f;
  for (int j = 0; j < SS; ++j) {
    float s = 0.f;
    #pragma unroll
    for (int d = 0; d < DH; ++d) s = fmaf(qreg[d], ksh[j][d], s);
    unsigned w32 = (j < 32) ? aw0 : (j < 64) ? aw1 : (j < 96) ? aw2 : aw3;
    s = (s + (((w32 >> (j & 31)) & 1u) ? qe1 : qe0)) * 0.125f;
    float mn = fmaxf(m, s);
    l = l * __expf(m - mn) + __expf(s - mn);
    m = mn;
  }

  // pass 2: recompute sims, accumulate attn@v and A1
  float acc[DH];
  #pragma unroll
  for (int d = 0; d < DH; ++d) acc[d] = 0.f;
  float A1 = 0.f;
  for (int j = 0; j < SS; ++j) {
    float s = 0.f;
    #pragma unroll
    for (int d = 0; d < DH; ++d) s = fmaf(qreg[d], ksh[j][d], s);
    unsigned w32 = (j < 32) ? aw0 : (j < 64) ? aw1 : (j < 96) ? aw2 : aw3;
    bool bit = ((w32 >> (j & 31)) & 1u) != 0;
    s = (s + (bit ? qe1 : qe0)) * 0.125f;
    float wgt = __expf(s - m);
    if (bit) A1 += wgt;
    const float* vrow = kv + ((size_t)(kk * SS + j)) * (2 * INNER) + INNER + h * DH;
    #pragma unroll
    for (int d = 0; d < DH; ++d) acc[d] = fmaf(wgt, vrow[d], acc[d]);
  }
  float invl = 1.f / l;
  A1 *= invl;
  float* op = outp + ((size_t)(kk * SS + i)) * INNER + h * DH;
  #pragma unroll
  for (int d = 0; d < DH; ++d)
    op[d] = acc[d] * invl + e0sh[d] + A1 * (e1sh[d] - e0sh[d]);
}

// ---------------- gated residual (scalar gate per row) ----------------

__global__ __launch_bounds__(256) void gated_residual_k(const float* __restrict__ a,
    const float* __restrict__ res, const int* __restrict__ cl,
    const float* __restrict__ w, float* __restrict__ outp) {
  __shared__ float red[8];
  int row = blockIdx.x;
  int c = threadIdx.x;
  float av = a[(size_t)row * CC + c];
  int node = cl ? cl[row] : row;
  float rv = res[(size_t)node * CC + c];
  float contrib = av * w[c] + rv * w[CC + c] + (av - rv) * w[2 * CC + c];
  float t, dummy;
  block_reduce2(contrib, 0.f, red, t, dummy);
  float gate = 1.f / (1.f + __expf(-t));
  outp[(size_t)row * CC + c] = av * gate + rv * (1.f - gate);
}

// ---------------- final scatter-add (disjoint partition -> plain write) ----------------

__global__ __launch_bounds__(256) void final_add(const float* __restrict__ x,
    const int* __restrict__ clusters, const float* __restrict__ nodes2, float* __restrict__ outp) {
  int row = blockIdx.x;
  int c = threadIdx.x;
  int node = clusters[row];
  outp[(size_t)node * CC + c] = x[(size_t)node * CC + c] + nodes2[(size_t)row * CC + c];
}

// ---------------- launch ----------------

extern "C" void kernel_launch(void* const* d_in, const int* in_sizes, int n_in,
                              void* d_out, int out_size, void* d_ws, size_t ws_size,
                              hipStream_t stream) {
  const float* x        = (const float*)d_in[0];
  const int*   edge_idx = (const int*)d_in[1];
  const int*   clusters = (const int*)d_in[2];
  const float* adj_emb  = (const float*)d_in[3];
  const float* ln1_g    = (const float*)d_in[4];
  const float* ln1_b    = (const float*)d_in[5];
  const float* Wq       = (const float*)d_in[6];
  const float* bq       = (const float*)d_in[7];
  const float* Wkv      = (const float*)d_in[8];
  const float* bkv      = (const float*)d_in[9];
  const float* We       = (const float*)d_in[10];
  const float* be       = (const float*)d_in[11];
  const float* Wo       = (const float*)d_in[12];
  const float* bo       = (const float*)d_in[13];
  const float* gate1_w  = (const float*)d_in[14];
  const float* ln2_g    = (const float*)d_in[15];
  const float* ln2_b    = (const float*)d_in[16];
  const float* W1       = (const float*)d_in[17];
  const float* b1       = (const float*)d_in[18];
  const float* W2       = (const float*)d_in[19];
  const float* b2       = (const float*)d_in[20];
  const float* gate2_w  = (const float*)d_in[21];
  float* out = (float*)d_out;

  char* ws = (char*)d_ws;
  int*      node2c = (int*)(ws + 0);          // 8KB
  int*      node2p = (int*)(ws + 8192);       // 8KB
  unsigned* adjb   = (unsigned*)(ws + 16384); // 32KB
  float*    e01    = (float*)(ws + 49152);    // 4KB
  size_t base = 65536;
  float* h      = (float*)(ws + base);                       // 2MB
  float* q      = (float*)(ws + base + (2ull << 20));        // 4MB
  float* kv     = (float*)(ws + base + (6ull << 20));        // 8MB
  float* attn_o = (float*)(ws + base + (14ull << 20));       // 4MB
  float* proj   = (float*)(ws + base + (18ull << 20));       // 2MB
  float* nodes1 = (float*)(ws + base + (20ull << 20));       // 2MB
  // aliases over dead regions
  float* h2     = attn_o;  // attn_o dead after out-proj GEMM
  float* ff1    = kv;      // kv dead after attention
  float* ff2    = q;       // q dead after attention
  float* nodes2 = h;       // h dead after QKV GEMMs
  if (ws_size < base + (22ull << 20)) return;  // workspace too small: fail loudly

  int E = in_sizes[1] / 2;

  hipMemsetAsync(adjb, 0, KK * SS * SS / 8, stream);
  build_maps<<<NN / 256, 256, 0, stream>>>(clusters, node2c, node2p);
  build_adj<<<(E + 255) / 256, 256, 0, stream>>>(edge_idx, node2c, node2p, adjb, E);
  ln_kernel<<<NN, 256, 0, stream>>>(x, clusters, ln1_g, ln1_b, h);
  e01_kernel<<<1, 512, 0, stream>>>(adj_emb, We, be, e01);
  gemm_rows<0, 4><<<dim3(NN / 4, 2), 256, 0, stream>>>(h, Wq, bq, q, CC, INNER);
  gemm_rows<0, 4><<<dim3(NN / 4, 4), 256, 0, stream>>>(h, Wkv, bkv, kv, CC, 2 * INNER);
  rotary_kernel<<<NN, 256, 0, stream>>>(q, kv);
  attn_kernel<<<KK * HH, 128, 0, stream>>>(q, kv, adjb, e01, attn_o);
  gemm_rows<0, 4><<<dim3(NN / 4, 1), 256, 0, stream>>>(attn_o, Wo, bo, proj, INNER, CC);
  gated_residual_k<<<NN, 256, 0, stream>>>(proj, x, clusters, gate1_w, nodes1);
  ln_kernel<<<NN, 256, 0, stream>>>(nodes1, nullptr, ln2_g, ln2_b, h2);
  gemm_rows<1, 4><<<dim3(NN / 4, 4), 256, 0, stream>>>(h2, W1, b1, ff1, CC, 4 * CC);
  gemm_rows<0, 4><<<dim3(NN / 4, 1), 256, 0, stream>>>(ff1, W2, b2, ff2, 4 * CC, CC);
  gated_residual_k<<<NN, 256, 0, stream>>>(ff2, nodes1, nullptr, gate2_w, nodes2);
  final_add<<<NN, 256, 0, stream>>>(x, clusters, nodes2, out);
}

// Round 3
// 219.907 us; speedup vs baseline: 3.3139x; 3.3139x over previous
//
#include <hip/hip_runtime.h>
#include <hip/hip_bf16.h>
#include <math.h>

#define NN 2048
#define CC 256
#define KK 16
#define SS 128
#define HH 8
#define DH 64
#define INNER 512

using short8 = __attribute__((ext_vector_type(8))) short;
using f32x4  = __attribute__((ext_vector_type(4))) float;
typedef __hip_bfloat16 bf16;

// ---------------- helpers ----------------

__device__ __forceinline__ void block_reduce2(float v1, float v2, float* red, float& o1, float& o2) {
  #pragma unroll
  for (int o = 32; o > 0; o >>= 1) { v1 += __shfl_xor(v1, o, 64); v2 += __shfl_xor(v2, o, 64); }
  int wid = threadIdx.x >> 6;
  if ((threadIdx.x & 63) == 0) { red[wid] = v1; red[4 + wid] = v2; }
  __syncthreads();
  o1 = red[0] + red[1] + red[2] + red[3];
  o2 = red[4] + red[5] + red[6] + red[7];
}

// ---------------- adjacency ----------------

__global__ void build_maps(const int* __restrict__ clusters, int* __restrict__ node2c,
                           int* __restrict__ node2p) {
  int r = blockIdx.x * 256 + threadIdx.x;
  int node = clusters[r];
  node2c[node] = r >> 7;
  node2p[node] = r & 127;
}

__global__ void build_adj(const int* __restrict__ ei, const int* __restrict__ node2c,
                          const int* __restrict__ node2p, unsigned* __restrict__ adj, int E) {
  int t = blockIdx.x * 256 + threadIdx.x;
  if (t >= E) return;
  int u = ei[t], v = ei[E + t];
  int cu = node2c[u];
  if (cu == node2c[v]) {
    int pu = node2p[u], pv = node2p[v];
    atomicOr(&adj[(cu * 128 + pu) * 4 + (pv >> 5)], 1u << (pv & 31));
  }
}

__global__ void e01_kernel(const float* __restrict__ adj_emb, const float* __restrict__ We,
                           const float* __restrict__ be, float* __restrict__ e01) {
  int j = threadIdx.x;  // 0..511
  float a0 = 0.f, a1 = 0.f;
  for (int c = 0; c < CC; ++c) {
    float w = We[(size_t)c * INNER + j];
    a0 = fmaf(adj_emb[c], w, a0);
    a1 = fmaf(adj_emb[CC + c], w, a1);
  }
  e01[j] = a0 + be[j];
  e01[INNER + j] = a1 + be[j];
}

// ---------------- weight convert + transpose:  Wt[n][k] = bf16(W[k][n]) ----------------

__global__ void convert_wt(const float* __restrict__ W, bf16* __restrict__ Wt, int Nd, int logK) {
  int idx = blockIdx.x * 256 + threadIdx.x;
  int n = idx >> logK, k = idx & ((1 << logK) - 1);
  Wt[idx] = __float2bfloat16(W[(size_t)k * Nd + n]);
}

// ---------------- layernorm (optional gather), bf16 output ----------------

__global__ __launch_bounds__(256) void ln_kernel(const float* __restrict__ src,
    const int* __restrict__ cl, const float* __restrict__ g, const float* __restrict__ b,
    bf16* __restrict__ outp) {
  __shared__ float red[8];
  int row = blockIdx.x;
  int node = cl ? cl[row] : row;
  int c = threadIdx.x;
  float v = src[(size_t)node * CC + c];
  float s, s2;
  block_reduce2(v, v * v, red, s, s2);
  float m = s * (1.f / CC);
  float var = s2 * (1.f / CC) - m * m;
  float r = rsqrtf(var + 1e-5f);
  outp[(size_t)row * CC + c] = __float2bfloat16((v - m) * r * g[c] + b[c]);
}

// ---------------- MFMA GEMM:  C[M,N] = A[M,K](bf16) @ Bt[N,K]^T(bf16) + bias ----------------
// 64x64 block tile, 4 waves, each wave 32x32 via 2x2 frags of 16x16x32.

template <int EPI, int OUTBF>
__global__ __launch_bounds__(256) void mfma_gemm(const bf16* __restrict__ A,
    const bf16* __restrict__ Bt, const float* __restrict__ bias, void* __restrict__ Cv,
    int Nd, int Kd) {
  int bm = blockIdx.x * 64;
  int bn = blockIdx.y * 64;
  int wave = threadIdx.x >> 6;
  int lane = threadIdx.x & 63;
  int wm = (wave & 1) * 32, wn = (wave >> 1) * 32;
  int lr = lane & 15;
  int lk = (lane >> 4) * 8;
  const bf16* pa0 = A + (size_t)(bm + wm + lr) * Kd + lk;
  const bf16* pa1 = pa0 + 16 * (size_t)Kd;
  const bf16* pb0 = Bt + (size_t)(bn + wn + lr) * Kd + lk;
  const bf16* pb1 = pb0 + 16 * (size_t)Kd;
  f32x4 acc00 = {0.f, 0.f, 0.f, 0.f}, acc01 = acc00, acc10 = acc00, acc11 = acc00;
  #pragma unroll 2
  for (int kb = 0; kb < Kd; kb += 32) {
    short8 a0 = *(const short8*)(pa0 + kb);
    short8 a1 = *(const short8*)(pa1 + kb);
    short8 b0 = *(const short8*)(pb0 + kb);
    short8 b1 = *(const short8*)(pb1 + kb);
    acc00 = __builtin_amdgcn_mfma_f32_16x16x32_bf16(a0, b0, acc00, 0, 0, 0);
    acc01 = __builtin_amdgcn_mfma_f32_16x16x32_bf16(a0, b1, acc01, 0, 0, 0);
    acc10 = __builtin_amdgcn_mfma_f32_16x16x32_bf16(a1, b0, acc10, 0, 0, 0);
    acc11 = __builtin_amdgcn_mfma_f32_16x16x32_bf16(a1, b1, acc11, 0, 0, 0);
  }
  int r0 = bm + wm + (lane >> 4) * 4;
  int c0 = bn + wn + (lane & 15);
  float bia0 = bias[c0];
  float bia1 = bias[c0 + 16];
  #pragma unroll
  for (int r = 0; r < 2; ++r) {
    #pragma unroll
    for (int c = 0; c < 2; ++c) {
      f32x4 av = (r == 0) ? (c == 0 ? acc00 : acc01) : (c == 0 ? acc10 : acc11);
      float bb = (c == 0) ? bia0 : bia1;
      #pragma unroll
      for (int i = 0; i < 4; ++i) {
        float v = av[i] + bb;
        if (EPI == 1) v = 0.5f * v * (1.f + erff(v * 0.70710678118654752f));
        size_t off = (size_t)(r0 + r * 16 + i) * Nd + (c0 + c * 16);
        if (OUTBF) ((bf16*)Cv)[off] = __float2bfloat16(v);
        else       ((float*)Cv)[off] = v;
      }
    }
  }
}

// ---------------- rotary (in-place on q and k-half of kv) ----------------

__global__ __launch_bounds__(256) void rotary_kernel(float* __restrict__ q, float* __restrict__ kv) {
  int row = blockIdx.x;
  int p = threadIdx.x;
  int head = p >> 5, tp = p & 31;
  int col = head * DH + tp * 2;
  float s = (float)(row & (SS - 1));
  float inv = powf(10000.f, -(float)tp / 32.f);
  float ang = s * inv;
  float cs, sn;
  sincosf(ang, &sn, &cs);   // sincosf(x, sin*, cos*)
  float* qp = q + (size_t)row * INNER + col;
  float x1 = qp[0], x2 = qp[1];
  qp[0] = x1 * cs - x2 * sn;
  qp[1] = x2 * cs + x1 * sn;
  float* kp = kv + (size_t)row * (2 * INNER) + col;
  x1 = kp[0]; x2 = kp[1];
  kp[0] = x1 * cs - x2 * sn;
  kp[1] = x2 * cs + x1 * sn;
}

// ---------------- attention: one block per (cluster, head), bf16 output ----------------

__global__ __launch_bounds__(128) void attn_kernel(const float* __restrict__ q,
    const float* __restrict__ kv, const unsigned* __restrict__ adj,
    const float* __restrict__ e01, bf16* __restrict__ outp) {
  __shared__ float ksh[SS][DH];
  __shared__ float e0sh[DH], e1sh[DH];
  int kk = blockIdx.x >> 3;
  int h = blockIdx.x & 7;
  int tid = threadIdx.x;

  for (int f = tid; f < SS * (DH / 4); f += 128) {
    int row = f >> 4, c4 = f & 15;
    const float4* src = (const float4*)(kv + ((size_t)(kk * SS + row)) * (2 * INNER) + h * DH) + c4;
    ((float4*)&ksh[0][0])[f] = *src;
  }
  if (tid < 64) e0sh[tid] = e01[h * DH + tid];
  else e1sh[tid - 64] = e01[INNER + h * DH + (tid - 64)];
  __syncthreads();

  int i = tid;
  float qreg[DH];
  const float4* qp = (const float4*)(q + ((size_t)(kk * SS + i)) * INNER + h * DH);
  #pragma unroll
  for (int d4 = 0; d4 < 16; ++d4) {
    float4 t = qp[d4];
    qreg[d4 * 4 + 0] = t.x; qreg[d4 * 4 + 1] = t.y;
    qreg[d4 * 4 + 2] = t.z; qreg[d4 * 4 + 3] = t.w;
  }
  float qe0 = 0.f, qe1 = 0.f;
  #pragma unroll
  for (int d = 0; d < DH; ++d) {
    qe0 = fmaf(qreg[d], e0sh[d], qe0);
    qe1 = fmaf(qreg[d], e1sh[d], qe1);
  }
  int rb = (kk * SS + i) * 4;
  unsigned aw0 = adj[rb + 0], aw1 = adj[rb + 1], aw2 = adj[rb + 2], aw3 = adj[rb + 3];

  float m = -1e30f, l = 0.f;
  for (int j = 0; j < SS; ++j) {
    float s = 0.f;
    #pragma unroll
    for (int d = 0; d < DH; ++d) s = fmaf(qreg[d], ksh[j][d], s);
    unsigned w32 = (j < 32) ? aw0 : (j < 64) ? aw1 : (j < 96) ? aw2 : aw3;
    s = (s + (((w32 >> (j & 31)) & 1u) ? qe1 : qe0)) * 0.125f;
    float mn = fmaxf(m, s);
    l = l * __expf(m - mn) + __expf(s - mn);
    m = mn;
  }

  float acc[DH];
  #pragma unroll
  for (int d = 0; d < DH; ++d) acc[d] = 0.f;
  float A1 = 0.f;
  for (int j = 0; j < SS; ++j) {
    float s = 0.f;
    #pragma unroll
    for (int d = 0; d < DH; ++d) s = fmaf(qreg[d], ksh[j][d], s);
    unsigned w32 = (j < 32) ? aw0 : (j < 64) ? aw1 : (j < 96) ? aw2 : aw3;
    bool bit = ((w32 >> (j & 31)) & 1u) != 0;
    s = (s + (bit ? qe1 : qe0)) * 0.125f;
    float wgt = __expf(s - m);
    if (bit) A1 += wgt;
    const float* vrow = kv + ((size_t)(kk * SS + j)) * (2 * INNER) + INNER + h * DH;
    #pragma unroll
    for (int d = 0; d < DH; ++d) acc[d] = fmaf(wgt, vrow[d], acc[d]);
  }
  float invl = 1.f / l;
  A1 *= invl;
  bf16* op = outp + ((size_t)(kk * SS + i)) * INNER + h * DH;
  #pragma unroll
  for (int d = 0; d < DH; ++d)
    op[d] = __float2bfloat16(acc[d] * invl + e0sh[d] + A1 * (e1sh[d] - e0sh[d]));
}

// ---------------- gated residual (scalar gate per row) ----------------

__global__ __launch_bounds__(256) void gated_residual_k(const float* __restrict__ a,
    const float* __restrict__ res, const int* __restrict__ cl,
    const float* __restrict__ w, float* __restrict__ outp) {
  __shared__ float red[8];
  int row = blockIdx.x;
  int c = threadIdx.x;
  float av = a[(size_t)row * CC + c];
  int node = cl ? cl[row] : row;
  float rv = res[(size_t)node * CC + c];
  float contrib = av * w[c] + rv * w[CC + c] + (av - rv) * w[2 * CC + c];
  float t, dummy;
  block_reduce2(contrib, 0.f, red, t, dummy);
  float gate = 1.f / (1.f + __expf(-t));
  outp[(size_t)row * CC + c] = av * gate + rv * (1.f - gate);
}

// ---------------- final add ----------------

__global__ __launch_bounds__(256) void final_add(const float* __restrict__ x,
    const int* __restrict__ clusters, const float* __restrict__ nodes2, float* __restrict__ outp) {
  int row = blockIdx.x;
  int c = threadIdx.x;
  int node = clusters[row];
  outp[(size_t)node * CC + c] = x[(size_t)node * CC + c] + nodes2[(size_t)row * CC + c];
}

// ---------------- launch ----------------

extern "C" void kernel_launch(void* const* d_in, const int* in_sizes, int n_in,
                              void* d_out, int out_size, void* d_ws, size_t ws_size,
                              hipStream_t stream) {
  const float* x        = (const float*)d_in[0];
  const int*   edge_idx = (const int*)d_in[1];
  const int*   clusters = (const int*)d_in[2];
  const float* adj_emb  = (const float*)d_in[3];
  const float* ln1_g    = (const float*)d_in[4];
  const float* ln1_b    = (const float*)d_in[5];
  const float* Wq       = (const float*)d_in[6];
  const float* bq       = (const float*)d_in[7];
  const float* Wkv      = (const float*)d_in[8];
  const float* bkv      = (const float*)d_in[9];
  const float* We       = (const float*)d_in[10];
  const float* be       = (const float*)d_in[11];
  const float* Wo       = (const float*)d_in[12];
  const float* bo       = (const float*)d_in[13];
  const float* gate1_w  = (const float*)d_in[14];
  const float* ln2_g    = (const float*)d_in[15];
  const float* ln2_b    = (const float*)d_in[16];
  const float* W1       = (const float*)d_in[17];
  const float* b1       = (const float*)d_in[18];
  const float* W2       = (const float*)d_in[19];
  const float* b2       = (const float*)d_in[20];
  const float* gate2_w  = (const float*)d_in[21];
  float* out = (float*)d_out;

  char* ws = (char*)d_ws;
  int*      node2c = (int*)(ws + 0);          // 8KB
  int*      node2p = (int*)(ws + 8192);       // 8KB
  unsigned* adjb   = (unsigned*)(ws + 16384); // 32KB
  float*    e01    = (float*)(ws + 49152);    // 4KB
  const size_t MB = 1ull << 20;
  size_t base = 65536;
  bf16*  h      = (bf16*) (ws + base);              // 1MB  [2048][256]
  float* q      = (float*)(ws + base + 1 * MB);     // 4MB  [2048][512]
  float* kv     = (float*)(ws + base + 5 * MB);     // 8MB  [2048][1024]
  bf16*  attn_o = (bf16*) (ws + base + 13 * MB);    // 2MB  [2048][512]
  float* proj   = (float*)(ws + base + 15 * MB);    // 2MB
  float* nodes1 = (float*)(ws + base + 17 * MB);    // 2MB
  bf16*  Wqt    = (bf16*) (ws + base + 19 * MB);              // 256KB [512][256]
  bf16*  Wkvt   = (bf16*) (ws + base + 19 * MB + 256 * 1024); // 512KB [1024][256]
  bf16*  Wot    = (bf16*) (ws + base + 19 * MB + 768 * 1024); // 256KB [256][512]
  bf16*  W1t    = (bf16*) (ws + base + 20 * MB);              // 512KB [1024][256]
  bf16*  W2t    = (bf16*) (ws + base + 20 * MB + 512 * 1024); // 512KB [256][1024]
  // aliases over dead regions
  bf16*  h2     = attn_o;                    // dead after out-proj GEMM
  bf16*  ff1    = (bf16*)kv;                 // kv dead after attention (4MB of 8)
  float* ff2    = q;                         // q dead after attention  (2MB of 4)
  float* nodes2 = (float*)(ws + base + 3 * MB);  // upper half of q region
  if (ws_size < base + 21 * MB) return;

  int E = in_sizes[1] / 2;

  hipMemsetAsync(adjb, 0, KK * SS * SS / 8, stream);
  build_maps<<<NN / 256, 256, 0, stream>>>(clusters, node2c, node2p);
  build_adj<<<(E + 255) / 256, 256, 0, stream>>>(edge_idx, node2c, node2p, adjb, E);
  e01_kernel<<<1, 512, 0, stream>>>(adj_emb, We, be, e01);
  convert_wt<<<512, 256, 0, stream>>>(Wq, Wqt, INNER, 8);        // [256][512] -> [512][256]
  convert_wt<<<1024, 256, 0, stream>>>(Wkv, Wkvt, 2 * INNER, 8); // [256][1024]-> [1024][256]
  convert_wt<<<512, 256, 0, stream>>>(Wo, Wot, CC, 9);           // [512][256] -> [256][512]
  convert_wt<<<1024, 256, 0, stream>>>(W1, W1t, 4 * CC, 8);      // [256][1024]-> [1024][256]
  convert_wt<<<1024, 256, 0, stream>>>(W2, W2t, CC, 10);         // [1024][256]-> [256][1024]
  ln_kernel<<<NN, 256, 0, stream>>>(x, clusters, ln1_g, ln1_b, h);
  mfma_gemm<0, 0><<<dim3(32, 8), 256, 0, stream>>>(h, Wqt, bq, q, INNER, CC);
  mfma_gemm<0, 0><<<dim3(32, 16), 256, 0, stream>>>(h, Wkvt, bkv, kv, 2 * INNER, CC);
  rotary_kernel<<<NN, 256, 0, stream>>>(q, kv);
  attn_kernel<<<KK * HH, 128, 0, stream>>>(q, kv, adjb, e01, attn_o);
  mfma_gemm<0, 0><<<dim3(32, 4), 256, 0, stream>>>(attn_o, Wot, bo, proj, CC, INNER);
  gated_residual_k<<<NN, 256, 0, stream>>>(proj, x, clusters, gate1_w, nodes1);
  ln_kernel<<<NN, 256, 0, stream>>>(nodes1, nullptr, ln2_g, ln2_b, h2);
  mfma_gemm<1, 1><<<dim3(32, 16), 256, 0, stream>>>(h2, W1t, b1, ff1, 4 * CC, CC);
  mfma_gemm<0, 0><<<dim3(32, 4), 256, 0, stream>>>(ff1, W2t, b2, ff2, CC, 4 * CC);
  gated_residual_k<<<NN, 256, 0, stream>>>(ff2, nodes1, nullptr, gate2_w, nodes2);
  final_add<<<NN, 256, 0, stream>>>(x, clusters, nodes2, out);
}

// Round 4
// 119.906 us; speedup vs baseline: 6.0777x; 1.8340x over previous
//
#include <hip/hip_runtime.h>
#include <hip/hip_bf16.h>
#include <math.h>

#define NN 2048
#define CC 256
#define KK 16
#define SS 128
#define HH 8
#define DH 64
#define INNER 512

using short8 = __attribute__((ext_vector_type(8))) short;
using f32x4  = __attribute__((ext_vector_type(4))) float;
typedef __hip_bfloat16 bf16;

__device__ __forceinline__ short f2bf(float f) {
  bf16 b = __float2bfloat16(f);
  short s; __builtin_memcpy(&s, &b, 2); return s;
}

// ---------------- helpers ----------------

__device__ __forceinline__ void block_reduce2(float v1, float v2, float* red, float& o1, float& o2) {
  #pragma unroll
  for (int o = 32; o > 0; o >>= 1) { v1 += __shfl_xor(v1, o, 64); v2 += __shfl_xor(v2, o, 64); }
  int wid = threadIdx.x >> 6;
  if ((threadIdx.x & 63) == 0) { red[wid] = v1; red[4 + wid] = v2; }
  __syncthreads();
  o1 = red[0] + red[1] + red[2] + red[3];
  o2 = red[4] + red[5] + red[6] + red[7];
}

// ---------------- adjacency ----------------

__global__ void build_maps(const int* __restrict__ clusters, int* __restrict__ node2c,
                           int* __restrict__ node2p) {
  int r = blockIdx.x * 256 + threadIdx.x;
  int node = clusters[r];
  node2c[node] = r >> 7;
  node2p[node] = r & 127;
}

__global__ void build_adj(const int* __restrict__ ei, const int* __restrict__ node2c,
                          const int* __restrict__ node2p, unsigned* __restrict__ adj, int E) {
  int t = blockIdx.x * 256 + threadIdx.x;
  if (t >= E) return;
  int u = ei[t], v = ei[E + t];
  int cu = node2c[u];
  if (cu == node2c[v]) {
    int pu = node2p[u], pv = node2p[v];
    atomicOr(&adj[(cu * 128 + pu) * 4 + (pv >> 5)], 1u << (pv & 31));
  }
}

__global__ void e01_kernel(const float* __restrict__ adj_emb, const float* __restrict__ We,
                           const float* __restrict__ be, float* __restrict__ e01) {
  int j = threadIdx.x;  // 0..511
  float a0 = 0.f, a1 = 0.f;
  for (int c = 0; c < CC; ++c) {
    float w = We[(size_t)c * INNER + j];
    a0 = fmaf(adj_emb[c], w, a0);
    a1 = fmaf(adj_emb[CC + c], w, a1);
  }
  e01[j] = a0 + be[j];
  e01[INNER + j] = a1 + be[j];
}

// ---------------- weight convert + transpose:  Wt[n][k] = bf16(W[k][n]) ----------------

__global__ void convert_wt(const float* __restrict__ W, bf16* __restrict__ Wt, int Nd, int logK) {
  int idx = blockIdx.x * 256 + threadIdx.x;
  int n = idx >> logK, k = idx & ((1 << logK) - 1);
  Wt[idx] = __float2bfloat16(W[(size_t)k * Nd + n]);
}

// ---------------- layernorm (optional gather), bf16 output ----------------

__global__ __launch_bounds__(256) void ln_kernel(const float* __restrict__ src,
    const int* __restrict__ cl, const float* __restrict__ g, const float* __restrict__ b,
    bf16* __restrict__ outp) {
  __shared__ float red[8];
  int row = blockIdx.x;
  int node = cl ? cl[row] : row;
  int c = threadIdx.x;
  float v = src[(size_t)node * CC + c];
  float s, s2;
  block_reduce2(v, v * v, red, s, s2);
  float m = s * (1.f / CC);
  float var = s2 * (1.f / CC) - m * m;
  float r = rsqrtf(var + 1e-5f);
  outp[(size_t)row * CC + c] = __float2bfloat16((v - m) * r * g[c] + b[c]);
}

// ---------------- MFMA GEMM:  C[M,N] = A[M,K](bf16) @ Bt[N,K]^T(bf16) + bias ----------------
// MODE 0: f32 out; MODE 1: gelu -> bf16 out; MODE 2: kv-split (col<512 f32 C1, else bf16 C2)

template <int MODE>
__global__ __launch_bounds__(256) void mfma_gemm(const bf16* __restrict__ A,
    const bf16* __restrict__ Bt, const float* __restrict__ bias,
    void* __restrict__ C1, void* __restrict__ C2, int Nd, int Kd) {
  int bm = blockIdx.x * 64;
  int bn = blockIdx.y * 64;
  int wave = threadIdx.x >> 6;
  int lane = threadIdx.x & 63;
  int wm = (wave & 1) * 32, wn = (wave >> 1) * 32;
  int lr = lane & 15;
  int lk = (lane >> 4) * 8;
  const bf16* pa0 = A + (size_t)(bm + wm + lr) * Kd + lk;
  const bf16* pa1 = pa0 + 16 * (size_t)Kd;
  const bf16* pb0 = Bt + (size_t)(bn + wn + lr) * Kd + lk;
  const bf16* pb1 = pb0 + 16 * (size_t)Kd;
  f32x4 acc00 = {0.f, 0.f, 0.f, 0.f}, acc01 = acc00, acc10 = acc00, acc11 = acc00;
  #pragma unroll 2
  for (int kb = 0; kb < Kd; kb += 32) {
    short8 a0 = *(const short8*)(pa0 + kb);
    short8 a1 = *(const short8*)(pa1 + kb);
    short8 b0 = *(const short8*)(pb0 + kb);
    short8 b1 = *(const short8*)(pb1 + kb);
    acc00 = __builtin_amdgcn_mfma_f32_16x16x32_bf16(a0, b0, acc00, 0, 0, 0);
    acc01 = __builtin_amdgcn_mfma_f32_16x16x32_bf16(a0, b1, acc01, 0, 0, 0);
    acc10 = __builtin_amdgcn_mfma_f32_16x16x32_bf16(a1, b0, acc10, 0, 0, 0);
    acc11 = __builtin_amdgcn_mfma_f32_16x16x32_bf16(a1, b1, acc11, 0, 0, 0);
  }
  int r0 = bm + wm + (lane >> 4) * 4;
  int c0 = bn + wn + lr;
  float bia0 = bias[c0];
  float bia1 = bias[c0 + 16];
  #pragma unroll
  for (int r = 0; r < 2; ++r) {
    #pragma unroll
    for (int c = 0; c < 2; ++c) {
      f32x4 av = (r == 0) ? (c == 0 ? acc00 : acc01) : (c == 0 ? acc10 : acc11);
      float bb = (c == 0) ? bia0 : bia1;
      int col = c0 + c * 16;
      #pragma unroll
      for (int i = 0; i < 4; ++i) {
        float v = av[i] + bb;
        size_t row = (size_t)(r0 + r * 16 + i);
        if (MODE == 1) {
          v = 0.5f * v * (1.f + erff(v * 0.70710678118654752f));
          ((bf16*)C1)[row * Nd + col] = __float2bfloat16(v);
        } else if (MODE == 2) {
          if (col < 512) ((float*)C1)[row * 512 + col] = v;
          else ((bf16*)C2)[row * 512 + (col - 512)] = __float2bfloat16(v);
        } else {
          ((float*)C1)[row * Nd + col] = v;
        }
      }
    }
  }
}

// ---------------- rotary: f32 q/k -> bf16 rotated qb/kb, plus qe0/qe1 dots ----------------

__global__ __launch_bounds__(256) void rotary2(const float* __restrict__ q,
    const float* __restrict__ kvk, const float* __restrict__ e01,
    bf16* __restrict__ qb, bf16* __restrict__ kbg,
    float* __restrict__ qe0g, float* __restrict__ qe1g) {
  int row = blockIdx.x;          // 0..2047
  int p = threadIdx.x;           // 0..255
  int h = p >> 5, tp = p & 31;
  int col = h * DH + tp * 2;
  float s = (float)(row & (SS - 1));
  float inv = exp2f(-(float)tp * 0.41524101186092029f);  // 10000^(-tp/32)
  float ang = s * inv;
  float cs, sn;
  sincosf(ang, &sn, &cs);
  size_t off = (size_t)row * INNER + col;
  float q0 = q[off], q1 = q[off + 1];
  float qr0 = q0 * cs - q1 * sn;
  float qr1 = q1 * cs + q0 * sn;
  qb[off]     = __float2bfloat16(qr0);
  qb[off + 1] = __float2bfloat16(qr1);
  float k0 = kvk[off], k1 = kvk[off + 1];
  kbg[off]     = __float2bfloat16(k0 * cs - k1 * sn);
  kbg[off + 1] = __float2bfloat16(k1 * cs + k0 * sn);
  // qe dots with rotated q (f32)
  float c0 = qr0 * e01[col] + qr1 * e01[col + 1];
  float c1 = qr0 * e01[INNER + col] + qr1 * e01[INNER + col + 1];
  #pragma unroll
  for (int o = 1; o <= 16; o <<= 1) { c0 += __shfl_xor(c0, o, 64); c1 += __shfl_xor(c1, o, 64); }
  if (tp == 0) {
    qe0g[h * NN + row] = c0;
    qe1g[h * NN + row] = c1;
  }
}

// ---------------- MFMA attention: block = (cluster, head, q-half), 4 waves x 16 rows ----------------

__global__ __launch_bounds__(256) void attn_mfma(const bf16* __restrict__ qb,
    const bf16* __restrict__ kbg, const bf16* __restrict__ vbg,
    const unsigned* __restrict__ adjb, const float* __restrict__ e01,
    const float* __restrict__ qe0g, const float* __restrict__ qe1g,
    bf16* __restrict__ attn_o) {
  __shared__ short Kb[SS][72];        // K rows [j][d], pitch 72 (16B-aligned, 2-way banks)
  __shared__ short Vt[DH][136];       // V transposed [d][j], pitch 136
  __shared__ short Psh[4][16][136];   // per-wave P strip [wave][row][j]
  __shared__ unsigned adjsh[SS][4];
  __shared__ float qe0sh[SS], qe1sh[SS], e0sh[DH], e1sh[DH];

  int blk = blockIdx.x;
  int half = blk & 1, h = (blk >> 1) & 7, c = blk >> 4;
  int tid = threadIdx.x;
  int w = tid >> 6, l = tid & 63;
  int lg = l >> 4, lr = l & 15;

  // ---- staging ----
  {
    int j = tid & 127, hd = tid >> 7;   // row j, d-half hd
    const short8* ksrc = (const short8*)(kbg + ((size_t)(c * SS + j)) * INNER + h * DH + hd * 32);
    const short8* vsrc = (const short8*)(vbg + ((size_t)(c * SS + j)) * INNER + h * DH + hd * 32);
    #pragma unroll
    for (int ch = 0; ch < 4; ++ch) {
      *(short8*)&Kb[j][hd * 32 + ch * 8] = ksrc[ch];
      short8 vv = vsrc[ch];
      #pragma unroll
      for (int e = 0; e < 8; ++e) Vt[hd * 32 + ch * 8 + e][j] = vv[e];
    }
  }
  if (tid < 128) {
    *(uint4*)&adjsh[tid][0] = *(const uint4*)(adjb + (size_t)(c * SS + tid) * 4);
    qe0sh[tid] = qe0g[h * NN + c * SS + tid];
    qe1sh[tid] = qe1g[h * NN + c * SS + tid];
  } else if (tid < 192) {
    e0sh[tid - 128] = e01[h * DH + (tid - 128)];
  } else {
    e1sh[tid - 192] = e01[INNER + h * DH + (tid - 192)];
  }
  __syncthreads();

  int ib = half * 64 + w * 16;  // strip base within cluster

  // ---- QK^T: S strip [16 x 128] ----
  const bf16* qrow = qb + ((size_t)(c * SS + ib + lr)) * INNER + h * DH + lg * 8;
  short8 aq0 = *(const short8*)(qrow);
  short8 aq1 = *(const short8*)(qrow + 32);
  f32x4 sacc[8];
  #pragma unroll
  for (int n = 0; n < 8; ++n) sacc[n] = (f32x4){0.f, 0.f, 0.f, 0.f};
  #pragma unroll
  for (int n = 0; n < 8; ++n) {
    short8 bk0 = *(const short8*)&Kb[16 * n + lr][lg * 8];
    short8 bk1 = *(const short8*)&Kb[16 * n + lr][lg * 8 + 32];
    sacc[n] = __builtin_amdgcn_mfma_f32_16x16x32_bf16(aq0, bk0, sacc[n], 0, 0, 0);
    sacc[n] = __builtin_amdgcn_mfma_f32_16x16x32_bf16(aq1, bk1, sacc[n], 0, 0, 0);
  }

  // ---- softmax on C-layout: lane owns rows 4*lg+ii, col lr+16n ----
  unsigned aw[4][4];
  float qe0r[4], qe1r[4];
  #pragma unroll
  for (int ii = 0; ii < 4; ++ii) {
    int i = ib + lg * 4 + ii;
    #pragma unroll
    for (int t = 0; t < 4; ++t) aw[ii][t] = adjsh[i][t];
    qe0r[ii] = qe0sh[i];
    qe1r[ii] = qe1sh[i];
  }
  float rmax[4] = {-1e30f, -1e30f, -1e30f, -1e30f};
  #pragma unroll
  for (int n = 0; n < 8; ++n) {
    unsigned word = aw[0][n >> 1];  // placeholder to keep structure; real per-ii below
    (void)word;
    #pragma unroll
    for (int ii = 0; ii < 4; ++ii) {
      unsigned bit = (aw[ii][n >> 1] >> (((n & 1) << 4) + lr)) & 1u;
      float sv = (sacc[n][ii] + (bit ? qe1r[ii] : qe0r[ii])) * 0.125f;
      sacc[n][ii] = sv;
      rmax[ii] = fmaxf(rmax[ii], sv);
    }
  }
  #pragma unroll
  for (int o = 1; o <= 8; o <<= 1) {
    #pragma unroll
    for (int ii = 0; ii < 4; ++ii) rmax[ii] = fmaxf(rmax[ii], __shfl_xor(rmax[ii], o, 64));
  }
  float lsum[4] = {0.f, 0.f, 0.f, 0.f}, a1[4] = {0.f, 0.f, 0.f, 0.f};
  #pragma unroll
  for (int n = 0; n < 8; ++n) {
    #pragma unroll
    for (int ii = 0; ii < 4; ++ii) {
      unsigned bit = (aw[ii][n >> 1] >> (((n & 1) << 4) + lr)) & 1u;
      float pv = __expf(sacc[n][ii] - rmax[ii]);
      lsum[ii] += pv;
      if (bit) a1[ii] += pv;
      Psh[w][lg * 4 + ii][16 * n + lr] = f2bf(pv);
    }
  }
  #pragma unroll
  for (int o = 1; o <= 8; o <<= 1) {
    #pragma unroll
    for (int ii = 0; ii < 4; ++ii) {
      lsum[ii] += __shfl_xor(lsum[ii], o, 64);
      a1[ii]   += __shfl_xor(a1[ii], o, 64);
    }
  }

  // ---- PV: out strip [16 x 64] ----
  f32x4 oacc[4];
  #pragma unroll
  for (int n = 0; n < 4; ++n) oacc[n] = (f32x4){0.f, 0.f, 0.f, 0.f};
  #pragma unroll
  for (int kb = 0; kb < 4; ++kb) {
    short8 pa = *(const short8*)&Psh[w][lr][kb * 32 + lg * 8];
    #pragma unroll
    for (int n = 0; n < 4; ++n) {
      short8 vb = *(const short8*)&Vt[16 * n + lr][kb * 32 + lg * 8];
      oacc[n] = __builtin_amdgcn_mfma_f32_16x16x32_bf16(pa, vb, oacc[n], 0, 0, 0);
    }
  }

  // ---- epilogue ----
  float e0r[4], e1r[4];
  #pragma unroll
  for (int n = 0; n < 4; ++n) { e0r[n] = e0sh[16 * n + lr]; e1r[n] = e1sh[16 * n + lr]; }
  #pragma unroll
  for (int ii = 0; ii < 4; ++ii) {
    float invl = 1.f / lsum[ii];
    float a1n = a1[ii] * invl;
    size_t row = (size_t)(c * SS + ib + lg * 4 + ii);
    #pragma unroll
    for (int n = 0; n < 4; ++n) {
      float val = oacc[n][ii] * invl + e0r[n] + a1n * (e1r[n] - e0r[n]);
      attn_o[row * INNER + h * DH + 16 * n + lr] = __float2bfloat16(val);
    }
  }
}

// ---------------- gated residual (scalar gate per row) ----------------

__global__ __launch_bounds__(256) void gated_residual_k(const float* __restrict__ a,
    const float* __restrict__ res, const int* __restrict__ cl,
    const float* __restrict__ w, float* __restrict__ outp) {
  __shared__ float red[8];
  int row = blockIdx.x;
  int c = threadIdx.x;
  float av = a[(size_t)row * CC + c];
  int node = cl ? cl[row] : row;
  float rv = res[(size_t)node * CC + c];
  float contrib = av * w[c] + rv * w[CC + c] + (av - rv) * w[2 * CC + c];
  float t, dummy;
  block_reduce2(contrib, 0.f, red, t, dummy);
  float gate = 1.f / (1.f + __expf(-t));
  outp[(size_t)row * CC + c] = av * gate + rv * (1.f - gate);
}

// ---------------- final add ----------------

__global__ __launch_bounds__(256) void final_add(const float* __restrict__ x,
    const int* __restrict__ clusters, const float* __restrict__ nodes2, float* __restrict__ outp) {
  int row = blockIdx.x;
  int c = threadIdx.x;
  int node = clusters[row];
  outp[(size_t)node * CC + c] = x[(size_t)node * CC + c] + nodes2[(size_t)row * CC + c];
}

// ---------------- launch ----------------

extern "C" void kernel_launch(void* const* d_in, const int* in_sizes, int n_in,
                              void* d_out, int out_size, void* d_ws, size_t ws_size,
                              hipStream_t stream) {
  const float* x        = (const float*)d_in[0];
  const int*   edge_idx = (const int*)d_in[1];
  const int*   clusters = (const int*)d_in[2];
  const float* adj_emb  = (const float*)d_in[3];
  const float* ln1_g    = (const float*)d_in[4];
  const float* ln1_b    = (const float*)d_in[5];
  const float* Wq       = (const float*)d_in[6];
  const float* bq       = (const float*)d_in[7];
  const float* Wkv      = (const float*)d_in[8];
  const float* bkv      = (const float*)d_in[9];
  const float* We       = (const float*)d_in[10];
  const float* be       = (const float*)d_in[11];
  const float* Wo       = (const float*)d_in[12];
  const float* bo       = (const float*)d_in[13];
  const float* gate1_w  = (const float*)d_in[14];
  const float* ln2_g    = (const float*)d_in[15];
  const float* ln2_b    = (const float*)d_in[16];
  const float* W1       = (const float*)d_in[17];
  const float* b1       = (const float*)d_in[18];
  const float* W2       = (const float*)d_in[19];
  const float* b2       = (const float*)d_in[20];
  const float* gate2_w  = (const float*)d_in[21];
  float* out = (float*)d_out;

  char* ws = (char*)d_ws;
  int*      node2c = (int*)(ws + 0);           // 8KB
  int*      node2p = (int*)(ws + 8192);        // 8KB
  unsigned* adjb   = (unsigned*)(ws + 16384);  // 32KB
  float*    e01    = (float*)(ws + 49152);     // 4KB
  float*    qe0g   = (float*)(ws + 53248);     // 64KB [8][2048]
  float*    qe1g   = (float*)(ws + 118784);    // 64KB
  const size_t MB = 1ull << 20;
  size_t base = 262144;
  char* w2 = ws + base;
  bf16*  h      = (bf16*) (w2 + 0 * MB);   // 1MB  [2048][256]
  float* q      = (float*)(w2 + 1 * MB);   // 4MB  [2048][512] (dead after rotary)
  float* kvk    = (float*)(w2 + 5 * MB);   // 4MB  [2048][512] k pre-rotary (dead after rotary)
  bf16*  vbg    = (bf16*) (w2 + 9 * MB);   // 2MB  [2048][512]
  bf16*  qb     = (bf16*) (w2 + 11 * MB);  // 2MB
  bf16*  kbg    = (bf16*) (w2 + 13 * MB);  // 2MB
  float* nodes1 = (float*)(w2 + 15 * MB);  // 2MB
  bf16*  Wqt    = (bf16*) (w2 + 17 * MB);
  bf16*  Wkvt   = (bf16*) (w2 + 17 * MB + 256 * 1024);
  bf16*  Wot    = (bf16*) (w2 + 17 * MB + 768 * 1024);
  bf16*  W1t    = (bf16*) (w2 + 18 * MB);
  bf16*  W2t    = (bf16*) (w2 + 18 * MB + 512 * 1024);
  // aliases over dead regions
  bf16*  attn_o = (bf16*) (w2 + 1 * MB);   // 2MB over q[0:2MB]
  float* proj   = (float*)(w2 + 3 * MB);   // 2MB over q[2:4MB]
  bf16*  h2     = (bf16*) (w2 + 1 * MB);   // 1MB, attn_o dead after Wo gemm
  bf16*  ff1    = (bf16*) (w2 + 5 * MB);   // 4MB over kvk
  float* ff2    = (float*)(w2 + 3 * MB);   // 2MB, proj dead after gate1
  float* nodes2 = (float*)(w2 + 7 * MB);   // 2MB, ff1 dead after W2 gemm
  if (ws_size < base + 19 * MB) return;

  int E = in_sizes[1] / 2;

  hipMemsetAsync(adjb, 0, KK * SS * SS / 8, stream);
  build_maps<<<NN / 256, 256, 0, stream>>>(clusters, node2c, node2p);
  build_adj<<<(E + 255) / 256, 256, 0, stream>>>(edge_idx, node2c, node2p, adjb, E);
  e01_kernel<<<1, 512, 0, stream>>>(adj_emb, We, be, e01);
  convert_wt<<<512, 256, 0, stream>>>(Wq, Wqt, INNER, 8);
  convert_wt<<<1024, 256, 0, stream>>>(Wkv, Wkvt, 2 * INNER, 8);
  convert_wt<<<512, 256, 0, stream>>>(Wo, Wot, CC, 9);
  convert_wt<<<1024, 256, 0, stream>>>(W1, W1t, 4 * CC, 8);
  convert_wt<<<1024, 256, 0, stream>>>(W2, W2t, CC, 10);
  ln_kernel<<<NN, 256, 0, stream>>>(x, clusters, ln1_g, ln1_b, h);
  mfma_gemm<0><<<dim3(32, 8), 256, 0, stream>>>(h, Wqt, bq, q, nullptr, INNER, CC);
  mfma_gemm<2><<<dim3(32, 16), 256, 0, stream>>>(h, Wkvt, bkv, kvk, vbg, 2 * INNER, CC);
  rotary2<<<NN, 256, 0, stream>>>(q, kvk, e01, qb, kbg, qe0g, qe1g);
  attn_mfma<<<256, 256, 0, stream>>>(qb, kbg, vbg, adjb, e01, qe0g, qe1g, attn_o);
  mfma_gemm<0><<<dim3(32, 4), 256, 0, stream>>>(attn_o, Wot, bo, proj, nullptr, CC, INNER);
  gated_residual_k<<<NN, 256, 0, stream>>>(proj, x, clusters, gate1_w, nodes1);
  ln_kernel<<<NN, 256, 0, stream>>>(nodes1, nullptr, ln2_g, ln2_b, h2);
  mfma_gemm<1><<<dim3(32, 16), 256, 0, stream>>>(h2, W1t, b1, ff1, nullptr, 4 * CC, CC);
  mfma_gemm<0><<<dim3(32, 4), 256, 0, stream>>>(ff1, W2t, b2, ff2, nullptr, CC, 4 * CC);
  gated_residual_k<<<NN, 256, 0, stream>>>(ff2, nodes1, nullptr, gate2_w, nodes2);
  final_add<<<NN, 256, 0, stream>>>(x, clusters, nodes2, out);
}

// Round 6
// 87.914 us; speedup vs baseline: 8.2894x; 1.3639x over previous
//
#include <hip/hip_runtime.h>
#include <hip/hip_bf16.h>
#include <math.h>

#define NN 2048
#define CC 256
#define KK 16
#define SS 128
#define HH 8
#define DH 64
#define INNER 512

using short8 = __attribute__((ext_vector_type(8))) short;
using f32x4  = __attribute__((ext_vector_type(4))) float;
typedef __hip_bfloat16 bf16;

__device__ __forceinline__ short f2bf(float f) {
  bf16 b = __float2bfloat16(f);
  short s; __builtin_memcpy(&s, &b, 2); return s;
}
__device__ __forceinline__ float bf2f(short s) {
  unsigned u = ((unsigned)(unsigned short)s) << 16;
  float f; __builtin_memcpy(&f, &u, 4); return f;
}

// ---------------- helpers ----------------

__device__ __forceinline__ void block_reduce1(float v1, float* red, float& o1) {
  #pragma unroll
  for (int o = 32; o > 0; o >>= 1) v1 += __shfl_xor(v1, o, 64);
  __syncthreads();  // protect red from any previous use
  int wid = threadIdx.x >> 6;
  if ((threadIdx.x & 63) == 0) red[wid] = v1;
  __syncthreads();
  o1 = red[0] + red[1] + red[2] + red[3];
}

__device__ __forceinline__ void block_reduce2(float v1, float v2, float* red, float& o1, float& o2) {
  #pragma unroll
  for (int o = 32; o > 0; o >>= 1) { v1 += __shfl_xor(v1, o, 64); v2 += __shfl_xor(v2, o, 64); }
  __syncthreads();
  int wid = threadIdx.x >> 6;
  if ((threadIdx.x & 63) == 0) { red[wid] = v1; red[4 + wid] = v2; }
  __syncthreads();
  o1 = red[0] + red[1] + red[2] + red[3];
  o2 = red[4] + red[5] + red[6] + red[7];
}

// ---------------- prep: maps + zero-adj + e01 + rope table + bias concat + weight converts ----
// BLOCK MAP (grid 4160):
//   [0,8)      node->cluster/pos maps
//   [8,40)     zero adjb: 32 blocks x 256 = 8192 words = 32KB  (EXACTLY adjb's size)
//   [40,42)    e01
//   [42,58)    rope table [128][32] float2
//   [58,64)    bqkv concat
//   [64,576)   Wq^T   [576,1600) Wkv^T   [1600,2112) Wo^T   [2112,3136) W1^T   [3136,4160) W2^T

__global__ __launch_bounds__(256) void prep(const int* __restrict__ clusters,
    const float* __restrict__ adj_emb, const float* __restrict__ We, const float* __restrict__ be,
    const float* __restrict__ Wq, const float* __restrict__ Wkv, const float* __restrict__ Wo,
    const float* __restrict__ W1, const float* __restrict__ W2,
    const float* __restrict__ bq, const float* __restrict__ bkv,
    int* __restrict__ node2c, int* __restrict__ node2p, unsigned* __restrict__ adjb,
    float* __restrict__ e01, float2* __restrict__ rope, float* __restrict__ bqkv,
    bf16* __restrict__ Wqkvt, bf16* __restrict__ Wot, bf16* __restrict__ W1t,
    bf16* __restrict__ W2t) {
  int b = blockIdx.x, tid = threadIdx.x;
  if (b < 8) {                                   // node->cluster/pos maps
    int r = b * 256 + tid;
    int node = clusters[r];
    node2c[node] = r >> 7;
    node2p[node] = r & 127;
  } else if (b < 40) {                           // zero adjacency bitmask: 8192 words total
    adjb[(b - 8) * 256 + tid] = 0u;
  } else if (b < 42) {                           // e0/e1 = adj_emb @ We + be
    int j = (b - 40) * 256 + tid;
    float a0 = 0.f, a1 = 0.f;
    for (int c = 0; c < CC; ++c) {
      float w = We[(size_t)c * INNER + j];
      a0 = fmaf(adj_emb[c], w, a0);
      a1 = fmaf(adj_emb[CC + c], w, a1);
    }
    e01[j] = a0 + be[j];
    e01[INNER + j] = a1 + be[j];
  } else if (b < 58) {                           // rope table [128][32] (cos, sin)
    int idx = (b - 42) * 256 + tid;
    int s = idx >> 5, t = idx & 31;
    float ang = (float)s * exp2f(-(float)t * 0.41524101186092029f);  // s * 10000^(-t/32)
    float sn, cs;
    sincosf(ang, &sn, &cs);
    rope[idx] = make_float2(cs, sn);
  } else if (b < 64) {                           // bias concat [1536]
    int idx = (b - 58) * 256 + tid;
    bqkv[idx] = idx < 512 ? bq[idx] : bkv[idx - 512];
  } else if (b < 576) {                          // Wq^T  -> Wqkvt rows [0,512)
    int idx = (b - 64) * 256 + tid;
    int n = idx >> 8, k = idx & 255;
    Wqkvt[idx] = __float2bfloat16(Wq[(size_t)k * 512 + n]);
  } else if (b < 1600) {                         // Wkv^T -> Wqkvt rows [512,1536)
    int idx = (b - 576) * 256 + tid;
    int n = idx >> 8, k = idx & 255;
    Wqkvt[512 * 256 + idx] = __float2bfloat16(Wkv[(size_t)k * 1024 + n]);
  } else if (b < 2112) {                         // Wo^T [256][512]
    int idx = (b - 1600) * 256 + tid;
    int n = idx >> 9, k = idx & 511;
    Wot[idx] = __float2bfloat16(Wo[(size_t)k * 256 + n]);
  } else if (b < 3136) {                         // W1^T [1024][256]
    int idx = (b - 2112) * 256 + tid;
    int n = idx >> 8, k = idx & 255;
    W1t[idx] = __float2bfloat16(W1[(size_t)k * 1024 + n]);
  } else {                                       // W2^T [256][1024]
    int idx = (b - 3136) * 256 + tid;
    int n = idx >> 10, k = idx & 1023;
    W2t[idx] = __float2bfloat16(W2[(size_t)k * 256 + n]);
  }
}

__global__ void build_adj(const int* __restrict__ ei, const int* __restrict__ node2c,
                          const int* __restrict__ node2p, unsigned* __restrict__ adj, int E) {
  int t = blockIdx.x * 256 + threadIdx.x;
  if (t >= E) return;
  int u = ei[t], v = ei[E + t];
  int cu = node2c[u];
  if (cu == node2c[v]) {
    int pu = node2p[u], pv = node2p[v];
    atomicOr(&adj[(cu * 128 + pu) * 4 + (pv >> 5)], 1u << (pv & 31));
  }
}

// ---------------- layernorm (gather), bf16 output ----------------

__global__ __launch_bounds__(256) void ln_kernel(const float* __restrict__ src,
    const int* __restrict__ cl, const float* __restrict__ g, const float* __restrict__ b,
    bf16* __restrict__ outp) {
  __shared__ float red[8];
  int row = blockIdx.x;
  int node = cl ? cl[row] : row;
  int c = threadIdx.x;
  float v = src[(size_t)node * CC + c];
  float s, s2;
  block_reduce2(v, v * v, red, s, s2);
  float m = s * (1.f / CC);
  float var = s2 * (1.f / CC) - m * m;
  float r = rsqrtf(var + 1e-5f);
  outp[(size_t)row * CC + c] = __float2bfloat16((v - m) * r * g[c] + b[c]);
}

// ---------------- MFMA GEMM ----------------
// MODE 0: f32 out C1. MODE 1: gelu -> bf16 C1.
// MODE 3: fused QKV (Nd=1536): cols [0,512) rotary->qb(C1), [512,1024) rotary->kbg(C2),
//         [1024,1536) ->vbg(C3). Rotation pairs via shfl_xor(1); rope table [128][32].

template <int MODE>
__global__ __launch_bounds__(256) void mfma_gemm(const bf16* __restrict__ A,
    const bf16* __restrict__ Bt, const float* __restrict__ bias,
    void* __restrict__ C1, void* __restrict__ C2, void* __restrict__ C3,
    const float2* __restrict__ rope, int Nd, int Kd) {
  int bm = blockIdx.x * 64;
  int bn = blockIdx.y * 64;
  int wave = threadIdx.x >> 6;
  int lane = threadIdx.x & 63;
  int wm = (wave & 1) * 32, wn = (wave >> 1) * 32;
  int lr = lane & 15;
  int lk = (lane >> 4) * 8;
  const bf16* pa0 = A + (size_t)(bm + wm + lr) * Kd + lk;
  const bf16* pa1 = pa0 + 16 * (size_t)Kd;
  const bf16* pb0 = Bt + (size_t)(bn + wn + lr) * Kd + lk;
  const bf16* pb1 = pb0 + 16 * (size_t)Kd;
  f32x4 acc00 = {0.f, 0.f, 0.f, 0.f}, acc01 = acc00, acc10 = acc00, acc11 = acc00;
  #pragma unroll 2
  for (int kb = 0; kb < Kd; kb += 32) {
    short8 a0 = *(const short8*)(pa0 + kb);
    short8 a1 = *(const short8*)(pa1 + kb);
    short8 b0 = *(const short8*)(pb0 + kb);
    short8 b1 = *(const short8*)(pb1 + kb);
    acc00 = __builtin_amdgcn_mfma_f32_16x16x32_bf16(a0, b0, acc00, 0, 0, 0);
    acc01 = __builtin_amdgcn_mfma_f32_16x16x32_bf16(a0, b1, acc01, 0, 0, 0);
    acc10 = __builtin_amdgcn_mfma_f32_16x16x32_bf16(a1, b0, acc10, 0, 0, 0);
    acc11 = __builtin_amdgcn_mfma_f32_16x16x32_bf16(a1, b1, acc11, 0, 0, 0);
  }
  int r0 = bm + wm + (lane >> 4) * 4;
  int c0 = bn + wn + lr;
  float bia0 = bias[c0];
  float bia1 = bias[c0 + 16];
  float vals[2][2][4];
  #pragma unroll
  for (int r = 0; r < 2; ++r) {
    #pragma unroll
    for (int c = 0; c < 2; ++c) {
      f32x4 av = (r == 0) ? (c == 0 ? acc00 : acc01) : (c == 0 ? acc10 : acc11);
      float bb = (c == 0) ? bia0 : bia1;
      #pragma unroll
      for (int i = 0; i < 4; ++i) vals[r][c][i] = av[i] + bb;
    }
  }
  if (MODE == 3) {
    int seg = c0 >> 9;  // block-uniform: 0=q, 1=k, 2=v
    if (seg == 2) {
      bf16* dst = (bf16*)C3;
      #pragma unroll
      for (int r = 0; r < 2; ++r)
        #pragma unroll
        for (int c = 0; c < 2; ++c)
          #pragma unroll
          for (int i = 0; i < 4; ++i)
            dst[(size_t)(r0 + r * 16 + i) * 512 + (c0 - 1024 + 16 * c)] =
                __float2bfloat16(vals[r][c][i]);
    } else {
      bf16* dst = seg ? (bf16*)C2 : (bf16*)C1;
      int colbase = c0 - seg * 512;
      #pragma unroll
      for (int r = 0; r < 2; ++r) {
        #pragma unroll
        for (int c = 0; c < 2; ++c) {
          int col = colbase + 16 * c;
          int tp = (col & 63) >> 1;
          bool odd = (col & 1) != 0;
          #pragma unroll
          for (int i = 0; i < 4; ++i) {
            int row = r0 + r * 16 + i;
            float v = vals[r][c][i];
            float p = __shfl_xor(v, 1, 64);          // partner col (col^1)
            float2 cssn = rope[(row & 127) * 32 + tp];
            float o = odd ? fmaf(v, cssn.x, p * cssn.y) : fmaf(v, cssn.x, -p * cssn.y);
            dst[(size_t)row * 512 + col] = __float2bfloat16(o);
          }
        }
      }
    }
  } else {
    #pragma unroll
    for (int r = 0; r < 2; ++r) {
      #pragma unroll
      for (int c = 0; c < 2; ++c) {
        int col = c0 + c * 16;
        #pragma unroll
        for (int i = 0; i < 4; ++i) {
          float v = vals[r][c][i];
          size_t row = (size_t)(r0 + r * 16 + i);
          if (MODE == 1) {
            v = 0.5f * v * (1.f + erff(v * 0.70710678118654752f));
            ((bf16*)C1)[row * Nd + col] = __float2bfloat16(v);
          } else {
            ((float*)C1)[row * Nd + col] = v;
          }
        }
      }
    }
  }
}

// ---------------- MFMA attention: block = (cluster, head, q-half), 4 waves x 16 rows ------

__global__ __launch_bounds__(256) void attn_mfma(const bf16* __restrict__ qb,
    const bf16* __restrict__ kbg, const bf16* __restrict__ vbg,
    const unsigned* __restrict__ adjb, const float* __restrict__ e01,
    bf16* __restrict__ attn_o) {
  __shared__ short Kb[SS][72];
  __shared__ short Vt[DH][136];
  __shared__ short Psh[4][16][136];
  __shared__ unsigned adjsh[SS][4];
  __shared__ float e0sh[DH], e1sh[DH];

  int blk = blockIdx.x;
  int half = blk & 1, h = (blk >> 1) & 7, c = blk >> 4;
  int tid = threadIdx.x;
  int w = tid >> 6, l = tid & 63;
  int lg = l >> 4, lr = l & 15;

  // ---- staging ----
  {
    int j = tid & 127, hd = tid >> 7;
    const short8* ksrc = (const short8*)(kbg + ((size_t)(c * SS + j)) * INNER + h * DH + hd * 32);
    const short8* vsrc = (const short8*)(vbg + ((size_t)(c * SS + j)) * INNER + h * DH + hd * 32);
    #pragma unroll
    for (int ch = 0; ch < 4; ++ch) {
      *(short8*)&Kb[j][hd * 32 + ch * 8] = ksrc[ch];
      short8 vv = vsrc[ch];
      #pragma unroll
      for (int e = 0; e < 8; ++e) Vt[hd * 32 + ch * 8 + e][j] = vv[e];
    }
  }
  if (tid < 128) {
    *(uint4*)&adjsh[tid][0] = *(const uint4*)(adjb + (size_t)(c * SS + tid) * 4);
  } else if (tid < 192) {
    e0sh[tid - 128] = e01[h * DH + (tid - 128)];
  } else {
    e1sh[tid - 192] = e01[INNER + h * DH + (tid - 192)];
  }
  __syncthreads();

  int ib = half * 64 + w * 16;

  // ---- Q frags + qe dots (rows ib+lr) ----
  const bf16* qrow = qb + ((size_t)(c * SS + ib + lr)) * INNER + h * DH + lg * 8;
  short8 aq0 = *(const short8*)(qrow);
  short8 aq1 = *(const short8*)(qrow + 32);
  float d0 = 0.f, d1 = 0.f;
  #pragma unroll
  for (int e = 0; e < 8; ++e) {
    float q0 = bf2f(aq0[e]), q1 = bf2f(aq1[e]);
    d0 += q0 * e0sh[lg * 8 + e] + q1 * e0sh[lg * 8 + 32 + e];
    d1 += q0 * e1sh[lg * 8 + e] + q1 * e1sh[lg * 8 + 32 + e];
  }
  d0 += __shfl_xor(d0, 16, 64); d0 += __shfl_xor(d0, 32, 64);
  d1 += __shfl_xor(d1, 16, 64); d1 += __shfl_xor(d1, 32, 64);

  // ---- QK^T ----
  f32x4 sacc[8];
  #pragma unroll
  for (int n = 0; n < 8; ++n) sacc[n] = (f32x4){0.f, 0.f, 0.f, 0.f};
  #pragma unroll
  for (int n = 0; n < 8; ++n) {
    short8 bk0 = *(const short8*)&Kb[16 * n + lr][lg * 8];
    short8 bk1 = *(const short8*)&Kb[16 * n + lr][lg * 8 + 32];
    sacc[n] = __builtin_amdgcn_mfma_f32_16x16x32_bf16(aq0, bk0, sacc[n], 0, 0, 0);
    sacc[n] = __builtin_amdgcn_mfma_f32_16x16x32_bf16(aq1, bk1, sacc[n], 0, 0, 0);
  }

  // ---- softmax on C-layout: lane owns rows lg*4+ii (within strip), col 16n+lr ----
  unsigned aw[4][4];
  float qe0r[4], qe1r[4];
  #pragma unroll
  for (int ii = 0; ii < 4; ++ii) {
    int i = ib + lg * 4 + ii;
    #pragma unroll
    for (int t = 0; t < 4; ++t) aw[ii][t] = adjsh[i][t];
    qe0r[ii] = __shfl(d0, lg * 4 + ii, 64);
    qe1r[ii] = __shfl(d1, lg * 4 + ii, 64);
  }
  float rmax[4] = {-1e30f, -1e30f, -1e30f, -1e30f};
  #pragma unroll
  for (int n = 0; n < 8; ++n) {
    #pragma unroll
    for (int ii = 0; ii < 4; ++ii) {
      unsigned bit = (aw[ii][n >> 1] >> (((n & 1) << 4) + lr)) & 1u;
      float sv = (sacc[n][ii] + (bit ? qe1r[ii] : qe0r[ii])) * 0.125f;
      sacc[n][ii] = sv;
      rmax[ii] = fmaxf(rmax[ii], sv);
    }
  }
  #pragma unroll
  for (int o = 1; o <= 8; o <<= 1) {
    #pragma unroll
    for (int ii = 0; ii < 4; ++ii) rmax[ii] = fmaxf(rmax[ii], __shfl_xor(rmax[ii], o, 64));
  }
  float lsum[4] = {0.f, 0.f, 0.f, 0.f}, a1[4] = {0.f, 0.f, 0.f, 0.f};
  #pragma unroll
  for (int n = 0; n < 8; ++n) {
    #pragma unroll
    for (int ii = 0; ii < 4; ++ii) {
      unsigned bit = (aw[ii][n >> 1] >> (((n & 1) << 4) + lr)) & 1u;
      float pv = __expf(sacc[n][ii] - rmax[ii]);
      lsum[ii] += pv;
      if (bit) a1[ii] += pv;
      Psh[w][lg * 4 + ii][16 * n + lr] = f2bf(pv);
    }
  }
  #pragma unroll
  for (int o = 1; o <= 8; o <<= 1) {
    #pragma unroll
    for (int ii = 0; ii < 4; ++ii) {
      lsum[ii] += __shfl_xor(lsum[ii], o, 64);
      a1[ii]   += __shfl_xor(a1[ii], o, 64);
    }
  }

  // ---- PV ----
  f32x4 oacc[4];
  #pragma unroll
  for (int n = 0; n < 4; ++n) oacc[n] = (f32x4){0.f, 0.f, 0.f, 0.f};
  #pragma unroll
  for (int kb = 0; kb < 4; ++kb) {
    short8 pa = *(const short8*)&Psh[w][lr][kb * 32 + lg * 8];
    #pragma unroll
    for (int n = 0; n < 4; ++n) {
      short8 vb = *(const short8*)&Vt[16 * n + lr][kb * 32 + lg * 8];
      oacc[n] = __builtin_amdgcn_mfma_f32_16x16x32_bf16(pa, vb, oacc[n], 0, 0, 0);
    }
  }

  // ---- epilogue ----
  float e0r[4], e1r[4];
  #pragma unroll
  for (int n = 0; n < 4; ++n) { e0r[n] = e0sh[16 * n + lr]; e1r[n] = e1sh[16 * n + lr]; }
  #pragma unroll
  for (int ii = 0; ii < 4; ++ii) {
    float invl = 1.f / lsum[ii];
    float a1n = a1[ii] * invl;
    size_t row = (size_t)(c * SS + ib + lg * 4 + ii);
    #pragma unroll
    for (int n = 0; n < 4; ++n) {
      float val = oacc[n][ii] * invl + e0r[n] + a1n * (e1r[n] - e0r[n]);
      attn_o[row * INNER + h * DH + 16 * n + lr] = __float2bfloat16(val);
    }
  }
}

// ---------------- gate1 + LN2 fused ----------------

__global__ __launch_bounds__(256) void gate1_ln2(const float* __restrict__ a,
    const float* __restrict__ x, const int* __restrict__ cl, const float* __restrict__ w,
    const float* __restrict__ g, const float* __restrict__ b,
    float* __restrict__ nodes1, bf16* __restrict__ h2) {
  __shared__ float red[8];
  int row = blockIdx.x;
  int c = threadIdx.x;
  float av = a[(size_t)row * CC + c];
  float rv = x[(size_t)cl[row] * CC + c];
  float contrib = av * w[c] + rv * w[CC + c] + (av - rv) * w[2 * CC + c];
  float t;
  block_reduce1(contrib, red, t);
  float gate = 1.f / (1.f + __expf(-t));
  float n1 = av * gate + rv * (1.f - gate);
  nodes1[(size_t)row * CC + c] = n1;
  float s, s2;
  block_reduce2(n1, n1 * n1, red, s, s2);
  float m = s * (1.f / CC);
  float var = s2 * (1.f / CC) - m * m;
  float r = rsqrtf(var + 1e-5f);
  h2[(size_t)row * CC + c] = __float2bfloat16((n1 - m) * r * g[c] + b[c]);
}

// ---------------- gate2 + final add fused ----------------

__global__ __launch_bounds__(256) void gate2_add(const float* __restrict__ a,
    const float* __restrict__ nodes1, const int* __restrict__ clusters,
    const float* __restrict__ w, const float* __restrict__ x, float* __restrict__ outp) {
  __shared__ float red[8];
  int row = blockIdx.x;
  int c = threadIdx.x;
  float av = a[(size_t)row * CC + c];
  float rv = nodes1[(size_t)row * CC + c];
  float contrib = av * w[c] + rv * w[CC + c] + (av - rv) * w[2 * CC + c];
  float t;
  block_reduce1(contrib, red, t);
  float gate = 1.f / (1.f + __expf(-t));
  float n2 = av * gate + rv * (1.f - gate);
  int node = clusters[row];
  outp[(size_t)node * CC + c] = x[(size_t)node * CC + c] + n2;
}

// ---------------- launch ----------------

extern "C" void kernel_launch(void* const* d_in, const int* in_sizes, int n_in,
                              void* d_out, int out_size, void* d_ws, size_t ws_size,
                              hipStream_t stream) {
  const float* x        = (const float*)d_in[0];
  const int*   edge_idx = (const int*)d_in[1];
  const int*   clusters = (const int*)d_in[2];
  const float* adj_emb  = (const float*)d_in[3];
  const float* ln1_g    = (const float*)d_in[4];
  const float* ln1_b    = (const float*)d_in[5];
  const float* Wq       = (const float*)d_in[6];
  const float* bq       = (const float*)d_in[7];
  const float* Wkv      = (const float*)d_in[8];
  const float* bkv      = (const float*)d_in[9];
  const float* We       = (const float*)d_in[10];
  const float* be       = (const float*)d_in[11];
  const float* Wo       = (const float*)d_in[12];
  const float* bo       = (const float*)d_in[13];
  const float* gate1_w  = (const float*)d_in[14];
  const float* ln2_g    = (const float*)d_in[15];
  const float* ln2_b    = (const float*)d_in[16];
  const float* W1       = (const float*)d_in[17];
  const float* b1       = (const float*)d_in[18];
  const float* W2       = (const float*)d_in[19];
  const float* b2       = (const float*)d_in[20];
  const float* gate2_w  = (const float*)d_in[21];
  float* out = (float*)d_out;

  char* ws = (char*)d_ws;
  int*      node2c = (int*)(ws + 0);            // 8KB
  int*      node2p = (int*)(ws + 8192);         // 8KB
  unsigned* adjb   = (unsigned*)(ws + 16384);   // 32KB [ws+16384, ws+49152)
  float*    e01    = (float*)(ws + 49152);      // 4KB
  float2*   rope   = (float2*)(ws + 53248);     // 32KB [128][32]
  float*    bqkv   = (float*)(ws + 86016);      // 6KB
  const size_t MB = 1ull << 20;
  char* w2 = ws + 131072;
  bf16*  h      = (bf16*) (w2 + 0 * MB);    // 1MB  [2048][256]
  bf16*  qb     = (bf16*) (w2 + 1 * MB);    // 2MB  [2048][512]
  bf16*  kbg    = (bf16*) (w2 + 3 * MB);    // 2MB
  bf16*  vbg    = (bf16*) (w2 + 5 * MB);    // 2MB
  bf16*  attn_o = (bf16*) (w2 + 7 * MB);    // 2MB
  float* proj   = (float*)(w2 + 9 * MB);    // 2MB
  float* nodes1 = (float*)(w2 + 11 * MB);   // 2MB
  bf16*  h2     = (bf16*) (w2 + 13 * MB);   // 1MB
  bf16*  ff1    = (bf16*) (w2 + 14 * MB);   // 4MB  [2048][1024]
  float* ff2    = (float*)(w2 + 18 * MB);   // 2MB
  bf16*  Wqkvt  = (bf16*) (w2 + 20 * MB);              // 768KB [1536][256]
  bf16*  Wot    = (bf16*) (w2 + 20 * MB + 768 * 1024); // 256KB [256][512]
  bf16*  W1t    = (bf16*) (w2 + 21 * MB);              // 512KB [1024][256]
  bf16*  W2t    = (bf16*) (w2 + 21 * MB + 512 * 1024); // 512KB [256][1024]
  if (ws_size < 131072 + 22 * MB) return;

  int E = in_sizes[1] / 2;

  prep<<<4160, 256, 0, stream>>>(clusters, adj_emb, We, be, Wq, Wkv, Wo, W1, W2, bq, bkv,
                                 node2c, node2p, adjb, e01, rope, bqkv,
                                 Wqkvt, Wot, W1t, W2t);
  build_adj<<<(E + 255) / 256, 256, 0, stream>>>(edge_idx, node2c, node2p, adjb, E);
  ln_kernel<<<NN, 256, 0, stream>>>(x, clusters, ln1_g, ln1_b, h);
  mfma_gemm<3><<<dim3(32, 24), 256, 0, stream>>>(h, Wqkvt, bqkv, qb, kbg, vbg, rope, 1536, CC);
  attn_mfma<<<256, 256, 0, stream>>>(qb, kbg, vbg, adjb, e01, attn_o);
  mfma_gemm<0><<<dim3(32, 4), 256, 0, stream>>>(attn_o, Wot, bo, proj, nullptr, nullptr,
                                                nullptr, CC, INNER);
  gate1_ln2<<<NN, 256, 0, stream>>>(proj, x, clusters, gate1_w, ln2_g, ln2_b, nodes1, h2);
  mfma_gemm<1><<<dim3(32, 16), 256, 0, stream>>>(h2, W1t, b1, ff1, nullptr, nullptr,
                                                 nullptr, 4 * CC, CC);
  mfma_gemm<0><<<dim3(32, 4), 256, 0, stream>>>(ff1, W2t, b2, ff2, nullptr, nullptr,
                                                nullptr, CC, 4 * CC);
  gate2_add<<<NN, 256, 0, stream>>>(ff2, nodes1, clusters, gate2_w, x, out);
}